// Round 2
// baseline (626.661 us; speedup 1.0000x reference)
//
#include <hip/hip_runtime.h>
#include <stdint.h>

typedef __bf16 bf16_t;
typedef __attribute__((ext_vector_type(8))) __bf16 bf16x8;
typedef __attribute__((ext_vector_type(4))) float f32x4;
typedef __attribute__((ext_vector_type(8))) unsigned short ushort8;
typedef __attribute__((ext_vector_type(4))) int int4v;
typedef __attribute__((ext_vector_type(4))) float float4v;

typedef const void __attribute__((address_space(1)))* gptr_t;
typedef void __attribute__((address_space(3)))* lptr_t;

__constant__ float NF4_CB[16] = {
    -1.0f, -0.6961928009986877f, -0.5250730514526367f, -0.39491748809814453f,
    -0.28444138169288635f, -0.18477343022823334f, -0.09105003625154495f, 0.0f,
    0.07958029955625534f, 0.16093020141124725f, 0.24611230194568634f,
    0.33791524171829224f, 0.44070982933044434f, 0.5626170039176941f,
    0.6848514676094055f, 1.0f};

__device__ __forceinline__ unsigned short f32_to_bf16_rne(float f) {
    unsigned int u = __float_as_uint(f);
    u += 0x7FFFu + ((u >> 16) & 1u);
    return (unsigned short)(u >> 16);
}

// Fused preprocessing. LDS codebook, 16 elements/thread.
__global__ void prep_kernel(const int* __restrict__ w_codes,
                            const float* __restrict__ w_absmax,
                            const float* __restrict__ x,
                            const int* __restrict__ b_codes,
                            const float* __restrict__ b_absmax,
                            unsigned short* __restrict__ outW,
                            unsigned short* __restrict__ outA,
                            float* __restrict__ outBias,
                            long w16, long x16, int nbias, long wb, long xb) {
    __shared__ float cb[16];
    if (threadIdx.x < 16) cb[threadIdx.x] = NF4_CB[threadIdx.x];
    __syncthreads();

    long blk = blockIdx.x;
    if (blk < wb) {
        long t = blk * blockDim.x + threadIdx.x;
        if (t >= w16) return;
        long base = t * 16;
        float am = w_absmax[t >> 2];
        int4v c0 = *(const int4v*)(w_codes + base);
        int4v c1 = *(const int4v*)(w_codes + base + 4);
        int4v c2 = *(const int4v*)(w_codes + base + 8);
        int4v c3 = *(const int4v*)(w_codes + base + 12);
        ushort8 v0, v1;
        v0[0] = f32_to_bf16_rne(cb[c0[0]] * am);
        v0[1] = f32_to_bf16_rne(cb[c0[1]] * am);
        v0[2] = f32_to_bf16_rne(cb[c0[2]] * am);
        v0[3] = f32_to_bf16_rne(cb[c0[3]] * am);
        v0[4] = f32_to_bf16_rne(cb[c1[0]] * am);
        v0[5] = f32_to_bf16_rne(cb[c1[1]] * am);
        v0[6] = f32_to_bf16_rne(cb[c1[2]] * am);
        v0[7] = f32_to_bf16_rne(cb[c1[3]] * am);
        v1[0] = f32_to_bf16_rne(cb[c2[0]] * am);
        v1[1] = f32_to_bf16_rne(cb[c2[1]] * am);
        v1[2] = f32_to_bf16_rne(cb[c2[2]] * am);
        v1[3] = f32_to_bf16_rne(cb[c2[3]] * am);
        v1[4] = f32_to_bf16_rne(cb[c3[0]] * am);
        v1[5] = f32_to_bf16_rne(cb[c3[1]] * am);
        v1[6] = f32_to_bf16_rne(cb[c3[2]] * am);
        v1[7] = f32_to_bf16_rne(cb[c3[3]] * am);
        *(ushort8*)(outW + base) = v0;
        *(ushort8*)(outW + base + 8) = v1;
    } else if (blk < wb + xb) {
        long t = (blk - wb) * blockDim.x + threadIdx.x;
        if (t >= x16) return;
        long base = t * 16;
        float4v f0 = *(const float4v*)(x + base);
        float4v f1 = *(const float4v*)(x + base + 4);
        float4v f2 = *(const float4v*)(x + base + 8);
        float4v f3 = *(const float4v*)(x + base + 12);
        ushort8 v0, v1;
        v0[0] = f32_to_bf16_rne(f0[0]);
        v0[1] = f32_to_bf16_rne(f0[1]);
        v0[2] = f32_to_bf16_rne(f0[2]);
        v0[3] = f32_to_bf16_rne(f0[3]);
        v0[4] = f32_to_bf16_rne(f1[0]);
        v0[5] = f32_to_bf16_rne(f1[1]);
        v0[6] = f32_to_bf16_rne(f1[2]);
        v0[7] = f32_to_bf16_rne(f1[3]);
        v1[0] = f32_to_bf16_rne(f2[0]);
        v1[1] = f32_to_bf16_rne(f2[1]);
        v1[2] = f32_to_bf16_rne(f2[2]);
        v1[3] = f32_to_bf16_rne(f2[3]);
        v1[4] = f32_to_bf16_rne(f3[0]);
        v1[5] = f32_to_bf16_rne(f3[1]);
        v1[6] = f32_to_bf16_rne(f3[2]);
        v1[7] = f32_to_bf16_rne(f3[3]);
        *(ushort8*)(outA + base) = v0;
        *(ushort8*)(outA + base + 8) = v1;
    } else {
        int o = (int)(blk - wb - xb) * blockDim.x + threadIdx.x;
        if (o >= nbias) return;
        outBias[o] = cb[b_codes[o]] * b_absmax[o >> 6];
    }
}

// ---------------------------------------------------------------------------
// 256x256 tile, BK=64, 512 threads (8 waves = 2M x 4N, 128x64 out each),
// double-buffered 128 KiB LDS, FINE-PHASE pipeline:
//   4 phases/K-tile, 16 MFMA each (quadrant Gray order 00->01->11->10),
//   one fenced raw s_barrier per phase, ds_read register-prefetch one phase
//   ahead (reads for p+1 issue before p's MFMAs -> LDS/MFMA pipes overlap),
//   staging for tile kt+1 issued 4+4 chunks in phases 0/1 (post-barrier),
//   vmcnt(0) at phase 2 (newest load is 1-2 phases old -> near-free),
//   first reads of kt+1 after phase-3 barrier. Proven race-free:
//   RAW: wait@p2 < barrier@p2 < reads@p3; WAR: readers' lgkm completes
//   before their barrier arrival < stagers' post-barrier issue.
// LDS layout/swizzle/fragment formulas identical to harness-verified R1.
// Register frag sets alternate statically (tile-parity unroll x2).
// Requires nt = K/64 even (K % 128 == 0).
// ---------------------------------------------------------------------------
#define BAR() do { asm volatile("" ::: "memory"); \
                   __builtin_amdgcn_s_barrier(); \
                   asm volatile("" ::: "memory"); } while (0)
#define VM0() asm volatile("s_waitcnt vmcnt(0)" ::: "memory")

#define LOAD_A(dst, i0, BASE) do { \
  _Pragma("unroll") for (int ii_ = 0; ii_ < 4; ++ii_) \
    _Pragma("unroll") for (int kh_ = 0; kh_ < 2; ++kh_) \
      dst[ii_][kh_] = *(const bf16x8*)&sAB[((aoff + ((i0) + ii_) * 1024) ^ (kh_ << 5)) + (BASE)]; \
} while (0)

#define LOAD_B(dst, n0, BASE) do { \
  _Pragma("unroll") for (int nn_ = 0; nn_ < 2; ++nn_) \
    _Pragma("unroll") for (int kh_ = 0; kh_ < 2; ++kh_) \
      dst[nn_][kh_] = *(const bf16x8*)&sAB[((boff + ((n0) + nn_) * 1024) ^ (kh_ << 5)) + (BASE)]; \
} while (0)

#define MFMA16(areg, breg, r, c) do { \
  __builtin_amdgcn_s_setprio(1); \
  _Pragma("unroll") for (int kh_ = 0; kh_ < 2; ++kh_) \
    _Pragma("unroll") for (int ii_ = 0; ii_ < 4; ++ii_) \
      _Pragma("unroll") for (int nn_ = 0; nn_ < 2; ++nn_) \
        acc[4*(r)+ii_][2*(c)+nn_] = __builtin_amdgcn_mfma_f32_16x16x32_bf16( \
            areg[ii_][kh_], breg[nn_][kh_], acc[4*(r)+ii_][2*(c)+nn_], 0, 0, 0); \
  __builtin_amdgcn_s_setprio(0); \
} while (0)

#define STAGE4(j0, BSEL) do { \
  bf16_t* d_ = dst0 + (BSEL) * 32768; \
  _Pragma("unroll") for (int j_ = 0; j_ < 4; ++j_) { \
    __builtin_amdgcn_global_load_lds((gptr_t)srcp[(j0) + j_], \
                                     (lptr_t)(d_ + ((j0) + j_) * 512), 16, 0, 0); \
    srcp[(j0) + j_] += 64; \
  } \
} while (0)

// One K-tile: CURB/NXTB = elem base of cur/next LDS buffer, NSEL = next buf
// index, B03 = b-set for quadrants c=0 (ph0,ph3), B12 = b-set for c=1
// (ph1,ph2; also receives next tile's b{0,1} at ph3). DOST/DOPF guard
// staging / next-tile prefetch on the final tiles.
#define TILE_BODY(CURB, NXTB, NSEL, B03, B12, DOST, DOPF) do { \
  /* ph0: quad(0,0) on aS0,B03; stage chunks 0..3; prefetch b{2,3}->B12 */ \
  BAR(); \
  if (DOST) STAGE4(0, NSEL); \
  LOAD_B(B12, 2, CURB); \
  MFMA16(aS0, B03, 0, 0); \
  /* ph1: quad(0,1) on aS0,B12; stage chunks 4..7; prefetch a{4..7}->aS1 */ \
  BAR(); \
  if (DOST) STAGE4(4, NSEL); \
  LOAD_A(aS1, 4, CURB); \
  MFMA16(aS0, B12, 0, 1); \
  /* ph2: quad(1,1) on aS1,B12; counted drain of next-tile stages */ \
  VM0(); \
  BAR(); \
  MFMA16(aS1, B12, 1, 1); \
  /* ph3: quad(1,0) on aS1,B03; prefetch next tile a{0..3}->aS0, b{0,1}->B12 */ \
  BAR(); \
  if (DOPF) { LOAD_A(aS0, 0, NXTB); LOAD_B(B12, 0, NXTB); } \
  MFMA16(aS1, B03, 1, 0); \
} while (0)

__global__ __launch_bounds__(512, 2) void gemm_bias_kernel_256x256_fp(
        const bf16_t* __restrict__ A, const bf16_t* __restrict__ B,
        const float* __restrict__ bias, float* __restrict__ C,
        int M, int N, int K) {
    __shared__ __align__(16) bf16_t sAB[65536];   // 128 KiB: 2 x (A 32KB + B 32KB)

    const int t = threadIdx.x;
    const int lane = t & 63;
    const int wave = t >> 6;                      // 0..7

    // Bijective XCD-aware swizzle (nwg % 8 == 0 here).
    const int nbx = gridDim.x;
    const int nwg = nbx * (int)gridDim.y;
    int flat = (int)blockIdx.y * nbx + (int)blockIdx.x;
    if ((nwg & 7) == 0) flat = (flat & 7) * (nwg >> 3) + (flat >> 3);
    const int tileM = (flat / nbx) * 256;
    const int tileN = (flat % nbx) * 256;

    // ---- staging addresses (verified R1 formulas) ----
    const int rloc = lane >> 3;
    const int jsw  = (lane & 7) ^ rloc;
    const bf16_t* srcp[8];
#pragma unroll
    for (int j = 0; j < 8; ++j) {
        int c = wave * 8 + j;                     // 0..63
        int isB = c >> 5;
        int r = (c & 31) * 8 + rloc;
        const bf16_t* base = isB ? (B + (size_t)(tileN + r) * K)
                                 : (A + (size_t)(tileM + r) * K);
        srcp[j] = base + jsw * 8;
    }
    bf16_t* dst0 = &sAB[wave * 4096 + lane * 8];

    // ---- fragment-read addresses (verified R1 formulas) ----
    const int wm = wave >> 2;                     // 0..1
    const int wn = wave & 3;                      // 0..3
    const int la = lane & 15;
    const int jA = lane >> 4;
    const int jj0 = (jA ^ (lane & 7)) * 8;
    const int aoff = (wm * 128 + la) * 64 + jj0;
    const int boff = 16384 + (wn * 64 + la) * 64 + jj0;

    f32x4 acc[8][4] = {};
    bf16x8 aS0[4][2], aS1[4][2], bX[2][2], bY[2][2];
    const int nt = K >> 6;                        // even, >= 2

    // Prologue: stage tile 0 into buf0, wait, read first quadrant's frags.
#pragma unroll
    for (int j = 0; j < 8; ++j) {
        __builtin_amdgcn_global_load_lds((gptr_t)srcp[j], (lptr_t)(dst0 + j * 512),
                                         16, 0, 0);
        srcp[j] += 64;
    }
    VM0();
    BAR();
    LOAD_A(aS0, 0, 0);
    LOAD_B(bX, 0, 0);

    for (int kt = 0; kt < nt; kt += 2) {
        // even tile kt: buf0 current, stage kt+1 -> buf1 (always exists)
        TILE_BODY(0, 32768, 1, bX, bY, true, true);
        // odd tile kt+1: buf1 current, stage/prefetch kt+2 -> buf0 if it exists
        const bool more = (kt + 2 < nt);
        TILE_BODY(32768, 0, 0, bY, bX, more, more);
    }

    const int col0 = tileN + wn * 64 + la;
    const int row0 = tileM + wm * 128 + jA * 4;
    float bv[4];
#pragma unroll
    for (int ni = 0; ni < 4; ++ni) bv[ni] = bias[col0 + ni * 16];
#pragma unroll
    for (int mi = 0; mi < 8; ++mi)
#pragma unroll
        for (int ni = 0; ni < 4; ++ni)
#pragma unroll
            for (int r = 0; r < 4; ++r)
                C[(size_t)(row0 + mi * 16 + r) * N + (col0 + ni * 16)] =
                    acc[mi][ni][r] + bv[ni];
}

// Fallback: 256x128 tile, 512 threads (session-verified, single-buffered).
__global__ __launch_bounds__(512) void gemm_bias_kernel_256(
        const bf16_t* __restrict__ A, const bf16_t* __restrict__ B,
        const float* __restrict__ bias, float* __restrict__ C,
        int M, int N, int K) {
    __shared__ __align__(16) bf16_t sAB[24576];

    const int t = threadIdx.x;
    const int lane = t & 63;
    const int wave = t >> 6;
    const int tileM = blockIdx.y * 256;
    const int tileN = blockIdx.x * 128;

    const int rloc = lane >> 3;
    const int jsw  = (lane & 7) ^ rloc;
    const bf16_t* srcp[6];
    bf16_t* dstp[6];
#pragma unroll
    for (int j = 0; j < 6; ++j) {
        int c = wave * 6 + j;
        int isB = (c >= 32);
        int r = (isB ? (c - 32) : c) * 8 + rloc;
        const bf16_t* base = isB ? (B + (size_t)(tileN + r) * K)
                                 : (A + (size_t)(tileM + r) * K);
        srcp[j] = base + jsw * 8;
        dstp[j] = &sAB[c * 512 + lane * 8];
    }

    const int wm = wave >> 1;
    const int wn = wave & 1;
    const int la = lane & 15;
    const int jA = lane >> 4;
    const int jj0 = (jA ^ (lane & 7)) * 8;
    const int aoff = (wm * 64 + la) * 64 + jj0;
    const int boff = 16384 + (wn * 64 + la) * 64 + jj0;

    f32x4 acc[4][4] = {};

    for (int kt = 0; kt < K; kt += 64) {
#pragma unroll
        for (int j = 0; j < 6; ++j) {
            __builtin_amdgcn_global_load_lds((gptr_t)(srcp[j]), (lptr_t)(dstp[j]),
                                             16, 0, 0);
            srcp[j] += 64;
        }
        __syncthreads();

#pragma unroll
        for (int kh = 0; kh < 2; ++kh) {
            const int kx = kh * 32;
            bf16x8 a[4], b[4];
#pragma unroll
            for (int i = 0; i < 4; ++i) a[i] = *(const bf16x8*)&sAB[(aoff + i * 1024) ^ kx];
#pragma unroll
            for (int i = 0; i < 4; ++i) b[i] = *(const bf16x8*)&sAB[(boff + i * 1024) ^ kx];
#pragma unroll
            for (int mi = 0; mi < 4; ++mi)
#pragma unroll
                for (int ni = 0; ni < 4; ++ni)
                    acc[mi][ni] = __builtin_amdgcn_mfma_f32_16x16x32_bf16(
                        a[mi], b[ni], acc[mi][ni], 0, 0, 0);
        }
        __syncthreads();
    }

    const int col0 = tileN + wn * 64 + la;
    const int row0 = tileM + wm * 64 + jA * 4;
    float bv[4];
#pragma unroll
    for (int ni = 0; ni < 4; ++ni) bv[ni] = bias[col0 + ni * 16];
#pragma unroll
    for (int mi = 0; mi < 4; ++mi)
#pragma unroll
        for (int ni = 0; ni < 4; ++ni)
#pragma unroll
            for (int r = 0; r < 4; ++r)
                C[(size_t)(row0 + mi * 16 + r) * N + (col0 + ni * 16)] =
                    acc[mi][ni][r] + bv[ni];
}

// Fallback: 128x128 tile, 256 threads (used only if M % 256 != 0).
__global__ void gemm_bias_kernel_128(const bf16_t* __restrict__ A,
                                     const bf16_t* __restrict__ B,
                                     const float* __restrict__ bias,
                                     float* __restrict__ C,
                                     int M, int N, int K) {
    __shared__ __align__(16) bf16_t sAB[16384];
    const int t = threadIdx.x;
    const int lane = t & 63;
    const int wave = t >> 6;
    const int tileM = blockIdx.y * 128;
    const int tileN = blockIdx.x * 128;

    const int rloc = lane >> 3;
    const int jsw  = (lane & 7) ^ rloc;
    const int chunk0 = wave * 8;
    const int isB = chunk0 >> 4;
    const int ci0 = chunk0 & 15;
    const int r0 = ci0 * 8 + rloc;
    const bf16_t* srcp = (isB ? (B + (size_t)(tileN + r0) * K)
                              : (A + (size_t)(tileM + r0) * K)) + jsw * 8;
    bf16_t* dstp = &sAB[isB * 8192 + ci0 * 512 + lane * 8];
    const size_t srcChunkStride = (size_t)8 * K;

    const int wm = wave >> 1;
    const int wn = wave & 1;
    const int la = lane & 15;
    const int jA = lane >> 4;
    const int jj0 = (jA ^ (lane & 7)) * 8;
    const int aoff = (wm * 64 + la) * 64 + jj0;
    const int boff = 8192 + (wn * 64 + la) * 64 + jj0;

    f32x4 acc[4][4] = {};
    for (int kt = 0; kt < K; kt += 64) {
#pragma unroll
        for (int j8 = 0; j8 < 8; ++j8)
            __builtin_amdgcn_global_load_lds((gptr_t)(srcp + j8 * srcChunkStride),
                                             (lptr_t)(dstp + j8 * 512), 16, 0, 0);
        srcp += 64;
        __syncthreads();
#pragma unroll
        for (int kh = 0; kh < 2; ++kh) {
            const int kx = kh * 32;
            bf16x8 a[4], b[4];
#pragma unroll
            for (int i = 0; i < 4; ++i) a[i] = *(const bf16x8*)&sAB[(aoff + i * 1024) ^ kx];
#pragma unroll
            for (int i = 0; i < 4; ++i) b[i] = *(const bf16x8*)&sAB[(boff + i * 1024) ^ kx];
#pragma unroll
            for (int mi = 0; mi < 4; ++mi)
#pragma unroll
                for (int ni = 0; ni < 4; ++ni)
                    acc[mi][ni] = __builtin_amdgcn_mfma_f32_16x16x32_bf16(
                        a[mi], b[ni], acc[mi][ni], 0, 0, 0);
        }
        __syncthreads();
    }
    const int col0 = tileN + wn * 64 + la;
    const int row0 = tileM + wm * 64 + jA * 4;
    float bv[4];
#pragma unroll
    for (int ni = 0; ni < 4; ++ni) bv[ni] = bias[col0 + ni * 16];
#pragma unroll
    for (int mi = 0; mi < 4; ++mi)
#pragma unroll
        for (int ni = 0; ni < 4; ++ni)
#pragma unroll
            for (int r = 0; r < 4; ++r)
                C[(size_t)(row0 + mi * 16 + r) * N + (col0 + ni * 16)] =
                    acc[mi][ni][r] + bv[ni];
}

extern "C" void kernel_launch(void* const* d_in, const int* in_sizes, int n_in,
                              void* d_out, int out_size, void* d_ws, size_t ws_size,
                              hipStream_t stream) {
    const float* x        = (const float*)d_in[0];
    const int*   w_codes  = (const int*)d_in[1];
    const float* w_absmax = (const float*)d_in[2];
    const int*   b_codes  = (const int*)d_in[3];
    const float* b_absmax = (const float*)d_in[4];
    float* out = (float*)d_out;

    const int  D_OUT = in_sizes[3];
    const long WK    = (long)in_sizes[1];
    const int  D_IN  = (int)(WK / D_OUT);
    const long xN    = (long)in_sizes[0];
    const int  M     = (int)(xN / D_IN);
    const int  N = D_OUT, K = D_IN;

    unsigned short* wsW = (unsigned short*)d_ws;
    unsigned short* wsA = wsW + (size_t)N * K;
    float* wsBias = (float*)(wsA + (size_t)M * K);

    long w16 = WK / 16;
    long x16 = xN / 16;
    long wb = (w16 + 255) / 256;
    long xb = (x16 + 255) / 256;
    long bb = (D_OUT + 255) / 256;
    prep_kernel<<<dim3((unsigned)(wb + xb + bb)), dim3(256), 0, stream>>>(
        w_codes, w_absmax, x, b_codes, b_absmax, wsW, wsA, wsBias,
        w16, x16, D_OUT, wb, xb);

    if (M % 256 == 0 && N % 256 == 0 && K % 128 == 0) {
        gemm_bias_kernel_256x256_fp<<<dim3(N / 256, M / 256), dim3(512), 0, stream>>>(
            (const bf16_t*)wsA, (const bf16_t*)wsW, wsBias, out, M, N, K);
    } else if (M % 256 == 0) {
        gemm_bias_kernel_256<<<dim3(N / 128, M / 256), dim3(512), 0, stream>>>(
            (const bf16_t*)wsA, (const bf16_t*)wsW, wsBias, out, M, N, K);
    } else {
        gemm_bias_kernel_128<<<dim3(N / 128, M / 128), dim3(256), 0, stream>>>(
            (const bf16_t*)wsA, (const bf16_t*)wsW, wsBias, out, M, N, K);
    }
}

// Round 4
// 507.349 us; speedup vs baseline: 1.2352x; 1.2352x over previous
//
#include <hip/hip_runtime.h>
#include <stdint.h>

typedef __bf16 bf16_t;
typedef __attribute__((ext_vector_type(8))) __bf16 bf16x8;
typedef __attribute__((ext_vector_type(4))) float f32x4;
typedef __attribute__((ext_vector_type(8))) unsigned short ushort8;
typedef __attribute__((ext_vector_type(4))) unsigned short us4;
typedef __attribute__((ext_vector_type(4))) int int4v;
typedef __attribute__((ext_vector_type(4))) float float4v;

typedef const void __attribute__((address_space(1)))* gptr_t;
typedef void __attribute__((address_space(3)))* lptr_t;

__constant__ float NF4_CB[16] = {
    -1.0f, -0.6961928009986877f, -0.5250730514526367f, -0.39491748809814453f,
    -0.28444138169288635f, -0.18477343022823334f, -0.09105003625154495f, 0.0f,
    0.07958029955625534f, 0.16093020141124725f, 0.24611230194568634f,
    0.33791524171829224f, 0.44070982933044434f, 0.5626170039176941f,
    0.6848514676094055f, 1.0f};

__device__ __forceinline__ unsigned short f32_to_bf16_rne(float f) {
    unsigned int u = __float_as_uint(f);
    u += 0x7FFFu + ((u >> 16) & 1u);
    return (unsigned short)(u >> 16);
}

// ---------------------------------------------------------------------------
// Coalesced grid-stride prep. Unit = 4 elements. Per unit-iteration:
//   W: int4v load (16B/lane, unit-stride across lanes), us4 store (8B).
//      absmax[u>>4]: one 4B word broadcast across 16 consecutive lanes.
//   X: float4v load (16B/lane unit-stride), us4 store.
//   bias: 1 element/unit.
// Unit ranges: [0,nW4) -> W, [nW4,nW4+nX4) -> X, rest -> bias.
// nW4 and nX4 are multiples of 256 here, so blocks stay branch-homogeneous.
// Old prep had 64B lane stride (thread owned 16 contiguous elems) -> each
// 16B load scattered the wave over 4KB; this version is 1KB/wave/instr.
// ---------------------------------------------------------------------------
__global__ __launch_bounds__(256) void prep_kernel2(
        const int* __restrict__ w_codes, const float* __restrict__ w_absmax,
        const float* __restrict__ x,
        const int* __restrict__ b_codes, const float* __restrict__ b_absmax,
        unsigned short* __restrict__ outW, unsigned short* __restrict__ outA,
        float* __restrict__ outBias,
        long nW4, long nX4, long nBias) {
    __shared__ float cb[16];
    if (threadIdx.x < 16) cb[threadIdx.x] = NF4_CB[threadIdx.x];
    __syncthreads();

    const long total = nW4 + nX4 + nBias;
    const long stride = (long)gridDim.x * blockDim.x;
    for (long u = (long)blockIdx.x * blockDim.x + threadIdx.x; u < total;
         u += stride) {
        if (u < nW4) {
            int4v c = *(const int4v*)(w_codes + u * 4);
            float am = w_absmax[u >> 4];          // 16 units / 64-elem block
            us4 v;
            v[0] = f32_to_bf16_rne(cb[c[0]] * am);
            v[1] = f32_to_bf16_rne(cb[c[1]] * am);
            v[2] = f32_to_bf16_rne(cb[c[2]] * am);
            v[3] = f32_to_bf16_rne(cb[c[3]] * am);
            *(us4*)(outW + u * 4) = v;
        } else if (u < nW4 + nX4) {
            long i = u - nW4;
            float4v f = *(const float4v*)(x + i * 4);
            us4 v;
            v[0] = f32_to_bf16_rne(f[0]);
            v[1] = f32_to_bf16_rne(f[1]);
            v[2] = f32_to_bf16_rne(f[2]);
            v[3] = f32_to_bf16_rne(f[3]);
            *(us4*)(outA + i * 4) = v;
        } else {
            long o = u - nW4 - nX4;
            outBias[o] = cb[b_codes[o]] * b_absmax[o >> 6];
        }
    }
}

// ---------------------------------------------------------------------------
// Session-verified main gemm (R0, 248 us): 256x128 tile, BK=64, 512 threads
// (8 waves, 4x2 of 64x64), 16x16x32 MFMA, XOR-swizzled LDS, glds width=16,
// single-buffered 48 KB LDS -> 3 blocks/CU; inter-block overlap gives 51%
// MfmaUtil. Byte-identical revert; do not touch the sync structure.
// ---------------------------------------------------------------------------
__global__ __launch_bounds__(512) void gemm_bias_kernel_256(
        const bf16_t* __restrict__ A, const bf16_t* __restrict__ B,
        const float* __restrict__ bias, float* __restrict__ C,
        int M, int N, int K) {
    __shared__ __align__(16) bf16_t sAB[24576];   // 48 KB

    const int t = threadIdx.x;
    const int lane = t & 63;
    const int wave = t >> 6;                      // 0..7
    const int tileM = blockIdx.y * 256;
    const int tileN = blockIdx.x * 128;

    const int rloc = lane >> 3;
    const int jsw  = (lane & 7) ^ rloc;
    const bf16_t* srcp[6];
    bf16_t* dstp[6];
#pragma unroll
    for (int j = 0; j < 6; ++j) {
        int c = wave * 6 + j;
        int isB = (c >= 32);
        int r = (isB ? (c - 32) : c) * 8 + rloc;
        const bf16_t* base = isB ? (B + (size_t)(tileN + r) * K)
                                 : (A + (size_t)(tileM + r) * K);
        srcp[j] = base + jsw * 8;
        dstp[j] = &sAB[c * 512 + lane * 8];
    }

    const int wm = wave >> 1;
    const int wn = wave & 1;
    const int la = lane & 15;
    const int jA = lane >> 4;
    const int jj0 = (jA ^ (lane & 7)) * 8;
    const int aoff = (wm * 64 + la) * 64 + jj0;
    const int boff = 16384 + (wn * 64 + la) * 64 + jj0;

    f32x4 acc[4][4] = {};

    for (int kt = 0; kt < K; kt += 64) {
#pragma unroll
        for (int j = 0; j < 6; ++j) {
            __builtin_amdgcn_global_load_lds((gptr_t)(srcp[j]), (lptr_t)(dstp[j]),
                                             16, 0, 0);
            srcp[j] += 64;
        }
        __syncthreads();

#pragma unroll
        for (int kh = 0; kh < 2; ++kh) {
            const int kx = kh * 32;
            bf16x8 a[4], b[4];
#pragma unroll
            for (int i = 0; i < 4; ++i) a[i] = *(const bf16x8*)&sAB[(aoff + i * 1024) ^ kx];
#pragma unroll
            for (int i = 0; i < 4; ++i) b[i] = *(const bf16x8*)&sAB[(boff + i * 1024) ^ kx];
#pragma unroll
            for (int mi = 0; mi < 4; ++mi)
#pragma unroll
                for (int ni = 0; ni < 4; ++ni)
                    acc[mi][ni] = __builtin_amdgcn_mfma_f32_16x16x32_bf16(
                        a[mi], b[ni], acc[mi][ni], 0, 0, 0);
        }
        __syncthreads();
    }

    const int col0 = tileN + wn * 64 + la;
    const int row0 = tileM + wm * 64 + jA * 4;
    float bv[4];
#pragma unroll
    for (int ni = 0; ni < 4; ++ni) bv[ni] = bias[col0 + ni * 16];
#pragma unroll
    for (int mi = 0; mi < 4; ++mi)
#pragma unroll
        for (int ni = 0; ni < 4; ++ni)
#pragma unroll
            for (int r = 0; r < 4; ++r)
                C[(size_t)(row0 + mi * 16 + r) * N + (col0 + ni * 16)] =
                    acc[mi][ni][r] + bv[ni];
}

// Fallback: 128x128 tile, 256 threads (used only if M % 256 != 0).
__global__ void gemm_bias_kernel_128(const bf16_t* __restrict__ A,
                                     const bf16_t* __restrict__ B,
                                     const float* __restrict__ bias,
                                     float* __restrict__ C,
                                     int M, int N, int K) {
    __shared__ __align__(16) bf16_t sAB[16384];
    const int t = threadIdx.x;
    const int lane = t & 63;
    const int wave = t >> 6;
    const int tileM = blockIdx.y * 128;
    const int tileN = blockIdx.x * 128;

    const int rloc = lane >> 3;
    const int jsw  = (lane & 7) ^ rloc;
    const int chunk0 = wave * 8;
    const int isB = chunk0 >> 4;
    const int ci0 = chunk0 & 15;
    const int r0 = ci0 * 8 + rloc;
    const bf16_t* srcp = (isB ? (B + (size_t)(tileN + r0) * K)
                              : (A + (size_t)(tileM + r0) * K)) + jsw * 8;
    bf16_t* dstp = &sAB[isB * 8192 + ci0 * 512 + lane * 8];
    const size_t srcChunkStride = (size_t)8 * K;

    const int wm = wave >> 1;
    const int wn = wave & 1;
    const int la = lane & 15;
    const int jA = lane >> 4;
    const int jj0 = (jA ^ (lane & 7)) * 8;
    const int aoff = (wm * 64 + la) * 64 + jj0;
    const int boff = 8192 + (wn * 64 + la) * 64 + jj0;

    f32x4 acc[4][4] = {};
    for (int kt = 0; kt < K; kt += 64) {
#pragma unroll
        for (int j8 = 0; j8 < 8; ++j8)
            __builtin_amdgcn_global_load_lds((gptr_t)(srcp + j8 * srcChunkStride),
                                             (lptr_t)(dstp + j8 * 512), 16, 0, 0);
        srcp += 64;
        __syncthreads();
#pragma unroll
        for (int kh = 0; kh < 2; ++kh) {
            const int kx = kh * 32;
            bf16x8 a[4], b[4];
#pragma unroll
            for (int i = 0; i < 4; ++i) a[i] = *(const bf16x8*)&sAB[(aoff + i * 1024) ^ kx];
#pragma unroll
            for (int i = 0; i < 4; ++i) b[i] = *(const bf16x8*)&sAB[(boff + i * 1024) ^ kx];
#pragma unroll
            for (int mi = 0; mi < 4; ++mi)
#pragma unroll
                for (int ni = 0; ni < 4; ++ni)
                    acc[mi][ni] = __builtin_amdgcn_mfma_f32_16x16x32_bf16(
                        a[mi], b[ni], acc[mi][ni], 0, 0, 0);
        }
        __syncthreads();
    }
    const int col0 = tileN + wn * 64 + la;
    const int row0 = tileM + wm * 64 + jA * 4;
    float bv[4];
#pragma unroll
    for (int ni = 0; ni < 4; ++ni) bv[ni] = bias[col0 + ni * 16];
#pragma unroll
    for (int mi = 0; mi < 4; ++mi)
#pragma unroll
        for (int ni = 0; ni < 4; ++ni)
#pragma unroll
            for (int r = 0; r < 4; ++r)
                C[(size_t)(row0 + mi * 16 + r) * N + (col0 + ni * 16)] =
                    acc[mi][ni][r] + bv[ni];
}

extern "C" void kernel_launch(void* const* d_in, const int* in_sizes, int n_in,
                              void* d_out, int out_size, void* d_ws, size_t ws_size,
                              hipStream_t stream) {
    const float* x        = (const float*)d_in[0];
    const int*   w_codes  = (const int*)d_in[1];
    const float* w_absmax = (const float*)d_in[2];
    const int*   b_codes  = (const int*)d_in[3];
    const float* b_absmax = (const float*)d_in[4];
    float* out = (float*)d_out;

    const int  D_OUT = in_sizes[3];
    const long WK    = (long)in_sizes[1];
    const int  D_IN  = (int)(WK / D_OUT);
    const long xN    = (long)in_sizes[0];
    const int  M     = (int)(xN / D_IN);
    const int  N = D_OUT, K = D_IN;

    unsigned short* wsW = (unsigned short*)d_ws;
    unsigned short* wsA = wsW + (size_t)N * K;
    float* wsBias = (float*)(wsA + (size_t)M * K);

    long nW4 = WK / 4;
    long nX4 = xN / 4;
    long nBias = D_OUT;
    long totalUnits = nW4 + nX4 + nBias;
    long nblk = (totalUnits + 255) / 256;
    if (nblk > 2048) nblk = 2048;
    prep_kernel2<<<dim3((unsigned)nblk), dim3(256), 0, stream>>>(
        w_codes, w_absmax, x, b_codes, b_absmax, wsW, wsA, wsBias,
        nW4, nX4, nBias);

    if (M % 256 == 0) {
        gemm_bias_kernel_256<<<dim3(N / 128, M / 256), dim3(512), 0, stream>>>(
            (const bf16_t*)wsA, (const bf16_t*)wsW, wsBias, out, M, N, K);
    } else {
        gemm_bias_kernel_128<<<dim3(N / 128, M / 128), dim3(256), 0, stream>>>(
            (const bf16_t*)wsA, (const bf16_t*)wsW, wsBias, out, M, N, K);
    }
}